// Round 1
// baseline (130.207 us; speedup 1.0000x reference)
//
#include <hip/hip_runtime.h>

#define K_SEL 16

// ---------------------------------------------------------------------------
// Kernel A: per-window L1-similarity + exact top-16 (fp64 ranking) + features
// grid: 1024 blocks = 64 windows x 16 pixel-groups; block = 1024 thr (16 waves)
// wave w handles pixel i = (blockIdx&15)*16 + w of window (blockIdx>>4)
// ---------------------------------------------------------------------------
__global__ __launch_bounds__(1024) void simtopk_kernel(
    const float* __restrict__ x,    // (64, 256, 32) fp32
    float* __restrict__ feat)       // (16384, 48)   [16 scores | 32 relpos]
{
    __shared__ float4 xs4[256 * 8];          // 32 KB, slot-swizzled rows
    const int tid  = threadIdx.x;
    const int win  = blockIdx.x >> 4;
    const int grp  = blockIdx.x & 15;
    const int lane = tid & 63;
    const int wv   = tid >> 6;

    // stage window (coalesced float4), swizzle slot = f ^ (j&7)
    const float4* gx = reinterpret_cast<const float4*>(x + (size_t)win * 8192);
    #pragma unroll
    for (int k = 0; k < 2; ++k) {
        int v = tid + k * 1024;              // 0..2047
        int j = v >> 3, f = v & 7;
        xs4[j * 8 + (f ^ (j & 7))] = gx[v];
    }
    __syncthreads();

    const int i = grp * 16 + wv;

    // broadcast-load row i, promote to fp64 (exact)
    double xi[32];
    #pragma unroll
    for (int f = 0; f < 8; ++f) {
        float4 av = xs4[i * 8 + (f ^ (i & 7))];
        xi[4*f+0] = (double)av.x; xi[4*f+1] = (double)av.y;
        xi[4*f+2] = (double)av.z; xi[4*f+3] = (double)av.w;
    }

    // fp64 |delta| sums: lane owns j = lane + 64q, q=0..3
    double s[4];
    #pragma unroll
    for (int q = 0; q < 4; ++q) {
        const int j  = q * 64 + lane;
        const int jb = j * 8, jm = j & 7;
        double acc = 0.0;
        #pragma unroll
        for (int f = 0; f < 8; ++f) {
            float4 bv = xs4[jb + (f ^ jm)];
            acc += fabs(xi[4*f+0] - (double)bv.x);
            acc += fabs(xi[4*f+1] - (double)bv.y);
            acc += fabs(xi[4*f+2] - (double)bv.z);
            acc += fabs(xi[4*f+3] - (double)bv.w);
        }
        s[q] = acc;
    }

    // exact top-16 (min s == max w), tie-break: smaller j first (top_k semantics)
    float my_score = 0.0f; int my_idx = 0;
    for (int k = 0; k < K_SEL; ++k) {
        double bv = s[0]; int bj = lane;
        if (s[1] < bv) { bv = s[1]; bj = lane + 64;  }
        if (s[2] < bv) { bv = s[2]; bj = lane + 128; }
        if (s[3] < bv) { bv = s[3]; bj = lane + 192; }
        #pragma unroll
        for (int m = 32; m >= 1; m >>= 1) {
            double ov = __shfl_xor(bv, m, 64);
            int    oj = __shfl_xor(bj, m, 64);
            if (ov < bv || (ov == bv && oj < bj)) { bv = ov; bj = oj; }
        }
        if (lane == k) { my_score = (float)(1.0 - bv * 0.03125); my_idx = bj; }
        if      (bj == lane      ) s[0] = 1e300;
        else if (bj == lane + 64 ) s[1] = 1e300;
        else if (bj == lane + 128) s[2] = 1e300;
        else if (bj == lane + 192) s[3] = 1e300;
    }

    if (lane < K_SEL) {
        const int gp = win * 256 + i;
        feat[gp * 48 + lane] = my_score;
        float dh = (float)((i >> 4) - (my_idx >> 4)) * (1.0f / 15.0f);
        float dw = (float)((i & 15) - (my_idx & 15)) * (1.0f / 15.0f);
        reinterpret_cast<float2*>(feat)[gp * 24 + 8 + lane] = make_float2(dh, dw);
    }
}

// ---------------------------------------------------------------------------
// Kernel B: both FFNs. block = 256 thr = 64 pixels x 4 neuron groups.
// lane = pixel (conflict-free LDS), g = tid>>6 wave-uniform -> scalar weights.
// ---------------------------------------------------------------------------
__global__ __launch_bounds__(256) void ffn_kernel(
    const float* __restrict__ x,     // (16384, 32)
    const float* __restrict__ feat,  // (16384, 48)
    const float* __restrict__ s0w, const float* __restrict__ s0b,   // 48x128
    const float* __restrict__ s1w, const float* __restrict__ s1b,   // 128x128
    const float* __restrict__ sow, const float* __restrict__ sob,   // 128x64
    const float* __restrict__ o0w, const float* __restrict__ o0b,   // 96x128
    const float* __restrict__ o1w, const float* __restrict__ o1b,   // 128x128
    const float* __restrict__ oow, const float* __restrict__ oob,   // 128x64
    float* __restrict__ out)         // (16384, 64)
{
    __shared__ float fs[64 * 49];        // feat, pad 49
    __shared__ float bufA[64 * 129];     // pad 129
    __shared__ float bufB[64 * 129];

    const int tid   = threadIdx.x;
    const int px    = tid & 63;
    const int g     = tid >> 6;                                   // wave-uniform
    const int n032  = __builtin_amdgcn_readfirstlane(g * 32);
    const int n016  = __builtin_amdgcn_readfirstlane(g * 16);
    const int pbase = blockIdx.x * 64;

    // stage feat rows (coalesced)
    {
        const float* fsrc = feat + (size_t)pbase * 48;
        #pragma unroll
        for (int k = 0; k < 12; ++k) {
            int idx = tid + k * 256;                 // 0..3071
            int p = idx / 48, c = idx - p * 48;
            fs[p * 49 + c] = fsrc[idx];
        }
    }
    __syncthreads();

    // L1: 48 -> 128, relu   (fs -> bufA)
    {
        float acc[32];
        #pragma unroll
        for (int n = 0; n < 32; ++n) acc[n] = s0b[n032 + n];
        for (int c = 0; c < 48; ++c) {
            float a = fs[px * 49 + c];
            const float* wr = s0w + c * 128 + n032;
            #pragma unroll
            for (int n = 0; n < 32; ++n) acc[n] = fmaf(a, wr[n], acc[n]);
        }
        #pragma unroll
        for (int n = 0; n < 32; ++n) bufA[px * 129 + n032 + n] = fmaxf(acc[n], 0.0f);
    }
    __syncthreads();

    // L2: 128 -> 128, relu  (bufA -> bufB)
    {
        float acc[32];
        #pragma unroll
        for (int n = 0; n < 32; ++n) acc[n] = s1b[n032 + n];
        for (int c = 0; c < 128; ++c) {
            float a = bufA[px * 129 + c];
            const float* wr = s1w + c * 128 + n032;
            #pragma unroll
            for (int n = 0; n < 32; ++n) acc[n] = fmaf(a, wr[n], acc[n]);
        }
        #pragma unroll
        for (int n = 0; n < 32; ++n) bufB[px * 129 + n032 + n] = fmaxf(acc[n], 0.0f);
    }
    __syncthreads();

    // L3: 128 -> 64 (no relu)  (bufB -> bufA[0..63] = sf)
    {
        float acc[16];
        #pragma unroll
        for (int n = 0; n < 16; ++n) acc[n] = sob[n016 + n];
        for (int c = 0; c < 128; ++c) {
            float a = bufB[px * 129 + c];
            const float* wr = sow + c * 64 + n016;
            #pragma unroll
            for (int n = 0; n < 16; ++n) acc[n] = fmaf(a, wr[n], acc[n]);
        }
        #pragma unroll
        for (int n = 0; n < 16; ++n) bufA[px * 129 + n016 + n] = acc[n];
    }
    __syncthreads();

    // L4: [x(32), sf(64)] = 96 -> 128, relu  (-> bufB)
    {
        float acc[32];
        #pragma unroll
        for (int n = 0; n < 32; ++n) acc[n] = o0b[n032 + n];
        const float* xr = x + (size_t)(pbase + px) * 32;
        for (int c = 0; c < 32; ++c) {
            float a = xr[c];
            const float* wr = o0w + c * 128 + n032;
            #pragma unroll
            for (int n = 0; n < 32; ++n) acc[n] = fmaf(a, wr[n], acc[n]);
        }
        for (int c = 0; c < 64; ++c) {
            float a = bufA[px * 129 + c];
            const float* wr = o0w + (32 + c) * 128 + n032;
            #pragma unroll
            for (int n = 0; n < 32; ++n) acc[n] = fmaf(a, wr[n], acc[n]);
        }
        #pragma unroll
        for (int n = 0; n < 32; ++n) bufB[px * 129 + n032 + n] = fmaxf(acc[n], 0.0f);
    }
    __syncthreads();

    // L5: 128 -> 128, relu  (bufB -> bufA)
    {
        float acc[32];
        #pragma unroll
        for (int n = 0; n < 32; ++n) acc[n] = o1b[n032 + n];
        for (int c = 0; c < 128; ++c) {
            float a = bufB[px * 129 + c];
            const float* wr = o1w + c * 128 + n032;
            #pragma unroll
            for (int n = 0; n < 32; ++n) acc[n] = fmaf(a, wr[n], acc[n]);
        }
        #pragma unroll
        for (int n = 0; n < 32; ++n) bufA[px * 129 + n032 + n] = fmaxf(acc[n], 0.0f);
    }
    __syncthreads();

    // L6: 128 -> 64 (+bias, no relu) -> out
    {
        float acc[16];
        #pragma unroll
        for (int n = 0; n < 16; ++n) acc[n] = oob[n016 + n];
        for (int c = 0; c < 128; ++c) {
            float a = bufA[px * 129 + c];
            const float* wr = oow + c * 64 + n016;
            #pragma unroll
            for (int n = 0; n < 16; ++n) acc[n] = fmaf(a, wr[n], acc[n]);
        }
        float* orow = out + (size_t)(pbase + px) * 64 + n016;
        #pragma unroll
        for (int n = 0; n < 16; ++n) orow[n] = acc[n];
    }
}

extern "C" void kernel_launch(void* const* d_in, const int* in_sizes, int n_in,
                              void* d_out, int out_size, void* d_ws, size_t ws_size,
                              hipStream_t stream) {
    const float* x    = (const float*)d_in[0];
    const float* s0w  = (const float*)d_in[1];
    const float* s0b  = (const float*)d_in[2];
    const float* s1w  = (const float*)d_in[3];
    const float* s1b  = (const float*)d_in[4];
    const float* sow  = (const float*)d_in[5];
    const float* sob  = (const float*)d_in[6];
    const float* o0w  = (const float*)d_in[7];
    const float* o0b  = (const float*)d_in[8];
    const float* o1w  = (const float*)d_in[9];
    const float* o1b  = (const float*)d_in[10];
    const float* oow  = (const float*)d_in[11];
    const float* oob  = (const float*)d_in[12];
    float* feat = (float*)d_ws;                  // 16384 * 48 fp32 = 3.1 MB
    float* out  = (float*)d_out;

    simtopk_kernel<<<1024, 1024, 0, stream>>>(x, feat);
    ffn_kernel<<<256, 256, 0, stream>>>(x, feat,
                                        s0w, s0b, s1w, s1b, sow, sob,
                                        o0w, o0b, o1w, o1b, oow, oob,
                                        out);
}

// Round 2
// 116.890 us; speedup vs baseline: 1.1139x; 1.1139x over previous
//
#include <hip/hip_runtime.h>

#define K_SEL 16

// ---------------------------------------------------------------------------
// Kernel A: per-window L1-similarity + exact top-16 (fp64 ranking) + features
// grid: 1024 blocks = 64 windows x 16 pixel-groups; block = 1024 thr (16 waves)
// wave w handles pixel i = (blockIdx&15)*16 + w of window (blockIdx>>4)
// ---------------------------------------------------------------------------
__global__ __launch_bounds__(1024) void simtopk_kernel(
    const float* __restrict__ x,    // (64, 256, 32) fp32
    float* __restrict__ feat)       // (16384, 48)   [16 scores | 32 relpos]
{
    __shared__ float4 xs4[256 * 8];          // 32 KB, slot-swizzled rows
    const int tid  = threadIdx.x;
    const int win  = blockIdx.x >> 4;
    const int grp  = blockIdx.x & 15;
    const int lane = tid & 63;
    const int wv   = tid >> 6;

    // stage window (coalesced float4), swizzle slot = f ^ (j&7)
    const float4* gx = reinterpret_cast<const float4*>(x + (size_t)win * 8192);
    #pragma unroll
    for (int k = 0; k < 2; ++k) {
        int v = tid + k * 1024;              // 0..2047
        int j = v >> 3, f = v & 7;
        xs4[j * 8 + (f ^ (j & 7))] = gx[v];
    }
    __syncthreads();

    const int i = grp * 16 + wv;

    // broadcast-load row i, promote to fp64 (exact)
    double xi[32];
    #pragma unroll
    for (int f = 0; f < 8; ++f) {
        float4 av = xs4[i * 8 + (f ^ (i & 7))];
        xi[4*f+0] = (double)av.x; xi[4*f+1] = (double)av.y;
        xi[4*f+2] = (double)av.z; xi[4*f+3] = (double)av.w;
    }

    // fp64 |delta| sums: lane owns j = lane + 64q, q=0..3
    double s[4];
    #pragma unroll
    for (int q = 0; q < 4; ++q) {
        const int j  = q * 64 + lane;
        const int jb = j * 8, jm = j & 7;
        double acc = 0.0;
        #pragma unroll
        for (int f = 0; f < 8; ++f) {
            float4 bv = xs4[jb + (f ^ jm)];
            acc += fabs(xi[4*f+0] - (double)bv.x);
            acc += fabs(xi[4*f+1] - (double)bv.y);
            acc += fabs(xi[4*f+2] - (double)bv.z);
            acc += fabs(xi[4*f+3] - (double)bv.w);
        }
        s[q] = acc;
    }

    // exact top-16 (min s == max w), tie-break: smaller j first (top_k semantics)
    float my_score = 0.0f; int my_idx = 0;
    for (int k = 0; k < K_SEL; ++k) {
        double bv = s[0]; int bj = lane;
        if (s[1] < bv) { bv = s[1]; bj = lane + 64;  }
        if (s[2] < bv) { bv = s[2]; bj = lane + 128; }
        if (s[3] < bv) { bv = s[3]; bj = lane + 192; }
        #pragma unroll
        for (int m = 32; m >= 1; m >>= 1) {
            double ov = __shfl_xor(bv, m, 64);
            int    oj = __shfl_xor(bj, m, 64);
            if (ov < bv || (ov == bv && oj < bj)) { bv = ov; bj = oj; }
        }
        if (lane == k) { my_score = (float)(1.0 - bv * 0.03125); my_idx = bj; }
        if      (bj == lane      ) s[0] = 1e300;
        else if (bj == lane + 64 ) s[1] = 1e300;
        else if (bj == lane + 128) s[2] = 1e300;
        else if (bj == lane + 192) s[3] = 1e300;
    }

    if (lane < K_SEL) {
        const int gp = win * 256 + i;
        feat[gp * 48 + lane] = my_score;
        float dh = (float)((i >> 4) - (my_idx >> 4)) * (1.0f / 15.0f);
        float dw = (float)((i & 15) - (my_idx & 15)) * (1.0f / 15.0f);
        reinterpret_cast<float2*>(feat)[gp * 24 + 8 + lane] = make_float2(dh, dw);
    }
}

// ---------------------------------------------------------------------------
// Kernel B v2: both FFNs. block = 1024 thr = 64 px (lane) x 16 waves.
// Wave wv owns neurons [8wv,8wv+8) for 128-wide layers, [4wv,4wv+4) for 64-wide.
// Weights via wave-uniform scalar loads; activations via ds_read_b128,
// LDS rows stride 33 float4 (odd) for minimal b128 bank aliasing.
// ---------------------------------------------------------------------------
template<int IN4, int STR4, int LDW, int NOUT>
__device__ __forceinline__ void ffn_layer(const float4* __restrict__ in4, int px,
                                          const float* __restrict__ W,
                                          const float* __restrict__ B,
                                          int nb, float* acc)
{
    #pragma unroll
    for (int n = 0; n < NOUT; ++n) acc[n] = B[nb + n];
    #pragma unroll 2
    for (int c4 = 0; c4 < IN4; ++c4) {
        float4 a4 = in4[px * STR4 + c4];
        const float* w0 = W + (4 * c4 + 0) * LDW + nb;
        const float* w1 = W + (4 * c4 + 1) * LDW + nb;
        const float* w2 = W + (4 * c4 + 2) * LDW + nb;
        const float* w3 = W + (4 * c4 + 3) * LDW + nb;
        #pragma unroll
        for (int n = 0; n < NOUT; ++n) {
            float a = acc[n];
            a = fmaf(a4.x, w0[n], a);
            a = fmaf(a4.y, w1[n], a);
            a = fmaf(a4.z, w2[n], a);
            a = fmaf(a4.w, w3[n], a);
            acc[n] = a;
        }
    }
}

__global__ __launch_bounds__(1024, 4) void ffn_kernel(
    const float* __restrict__ x,     // (16384, 32)
    const float* __restrict__ feat,  // (16384, 48)
    const float* __restrict__ s0w, const float* __restrict__ s0b,   // 48x128
    const float* __restrict__ s1w, const float* __restrict__ s1b,   // 128x128
    const float* __restrict__ sow, const float* __restrict__ sob,   // 128x64
    const float* __restrict__ o0w, const float* __restrict__ o0b,   // 96x128
    const float* __restrict__ o1w, const float* __restrict__ o1b,   // 128x128
    const float* __restrict__ oow, const float* __restrict__ oob,   // 128x64
    float* __restrict__ out)         // (16384, 64)
{
    __shared__ float4 fs4[64 * 13];      // feat rows, 12 f4 + 1 pad
    __shared__ float4 A4[64 * 33];       // 32 f4 + 1 pad
    __shared__ float4 B4[64 * 33];

    const int tid   = threadIdx.x;
    const int px    = tid & 63;
    const int wv    = tid >> 6;                                  // 0..15
    const int nb8   = __builtin_amdgcn_readfirstlane(wv * 8);
    const int nb4   = __builtin_amdgcn_readfirstlane(wv * 4);
    const int sl8   = __builtin_amdgcn_readfirstlane(wv * 2);    // f4 slot for 8-neuron grp
    const int slsf  = __builtin_amdgcn_readfirstlane(8 + wv);    // f4 slot for sf grp
    const int pbase = blockIdx.x * 64;

    // stage feat rows (coalesced float4): 64 px x 12 f4 = 768
    if (tid < 768) {
        int p = tid / 12, f = tid - p * 12;
        fs4[p * 13 + f] = reinterpret_cast<const float4*>(feat)[(size_t)pbase * 12 + tid];
    }
    __syncthreads();

    float acc[8];

    // L1: 48 -> 128 relu   (fs4 -> A4 slots 0..31)
    ffn_layer<12, 13, 128, 8>(fs4, px, s0w, s0b, nb8, acc);
    A4[px * 33 + sl8    ] = make_float4(fmaxf(acc[0],0.f), fmaxf(acc[1],0.f), fmaxf(acc[2],0.f), fmaxf(acc[3],0.f));
    A4[px * 33 + sl8 + 1] = make_float4(fmaxf(acc[4],0.f), fmaxf(acc[5],0.f), fmaxf(acc[6],0.f), fmaxf(acc[7],0.f));
    __syncthreads();

    // L2: 128 -> 128 relu  (A4 -> B4)
    ffn_layer<32, 33, 128, 8>(A4, px, s1w, s1b, nb8, acc);
    B4[px * 33 + sl8    ] = make_float4(fmaxf(acc[0],0.f), fmaxf(acc[1],0.f), fmaxf(acc[2],0.f), fmaxf(acc[3],0.f));
    B4[px * 33 + sl8 + 1] = make_float4(fmaxf(acc[4],0.f), fmaxf(acc[5],0.f), fmaxf(acc[6],0.f), fmaxf(acc[7],0.f));
    __syncthreads();

    // Phase 3: stage x into A4 slots 0..7  +  L3: 128 -> 64 (sf, no relu) into A4 slots 8..23
    if (tid < 512) {
        int p = tid >> 3, f = tid & 7;
        A4[p * 33 + f] = reinterpret_cast<const float4*>(x)[(size_t)(pbase + p) * 8 + f];
    }
    ffn_layer<32, 33, 64, 4>(B4, px, sow, sob, nb4, acc);
    A4[px * 33 + slsf] = make_float4(acc[0], acc[1], acc[2], acc[3]);
    __syncthreads();

    // L4: [x(32) | sf(64)] = 96 -> 128 relu  (A4 slots 0..23 -> B4); weight row = 4*c4+cc
    ffn_layer<24, 33, 128, 8>(A4, px, o0w, o0b, nb8, acc);
    B4[px * 33 + sl8    ] = make_float4(fmaxf(acc[0],0.f), fmaxf(acc[1],0.f), fmaxf(acc[2],0.f), fmaxf(acc[3],0.f));
    B4[px * 33 + sl8 + 1] = make_float4(fmaxf(acc[4],0.f), fmaxf(acc[5],0.f), fmaxf(acc[6],0.f), fmaxf(acc[7],0.f));
    __syncthreads();

    // L5: 128 -> 128 relu  (B4 -> A4)
    ffn_layer<32, 33, 128, 8>(B4, px, o1w, o1b, nb8, acc);
    A4[px * 33 + sl8    ] = make_float4(fmaxf(acc[0],0.f), fmaxf(acc[1],0.f), fmaxf(acc[2],0.f), fmaxf(acc[3],0.f));
    A4[px * 33 + sl8 + 1] = make_float4(fmaxf(acc[4],0.f), fmaxf(acc[5],0.f), fmaxf(acc[6],0.f), fmaxf(acc[7],0.f));
    __syncthreads();

    // L6: 128 -> 64 (+bias, no relu) -> out (float4 per thread)
    ffn_layer<32, 33, 64, 4>(A4, px, oow, oob, nb4, acc);
    reinterpret_cast<float4*>(out)[(size_t)(pbase + px) * 16 + (nb4 >> 2)] =
        make_float4(acc[0], acc[1], acc[2], acc[3]);
}

extern "C" void kernel_launch(void* const* d_in, const int* in_sizes, int n_in,
                              void* d_out, int out_size, void* d_ws, size_t ws_size,
                              hipStream_t stream) {
    const float* x    = (const float*)d_in[0];
    const float* s0w  = (const float*)d_in[1];
    const float* s0b  = (const float*)d_in[2];
    const float* s1w  = (const float*)d_in[3];
    const float* s1b  = (const float*)d_in[4];
    const float* sow  = (const float*)d_in[5];
    const float* sob  = (const float*)d_in[6];
    const float* o0w  = (const float*)d_in[7];
    const float* o0b  = (const float*)d_in[8];
    const float* o1w  = (const float*)d_in[9];
    const float* o1b  = (const float*)d_in[10];
    const float* oow  = (const float*)d_in[11];
    const float* oob  = (const float*)d_in[12];
    float* feat = (float*)d_ws;                  // 16384 * 48 fp32 = 3.1 MB
    float* out  = (float*)d_out;

    simtopk_kernel<<<1024, 1024, 0, stream>>>(x, feat);
    ffn_kernel<<<256, 1024, 0, stream>>>(x, feat,
                                         s0w, s0b, s1w, s1b, sow, sob,
                                         o0w, o0b, o1w, o1b, oow, oob,
                                         out);
}

// Round 3
// 94.499 us; speedup vs baseline: 1.3779x; 1.2370x over previous
//
#include <hip/hip_runtime.h>

#define K_SEL 16
#define NCAND 20   // top-20 preselect, fp64 re-rank -> exact top-16 order

// ---------------------------------------------------------------------------
// Kernel A v3: fp32 distance pass + packed-u32 top-20 preselect + fp64 re-rank
// grid: 1024 blocks = 64 windows x 16 pixel-groups; block = 1024 thr (16 waves)
// wave wv handles pixel i = (blockIdx&15)*16 + wv of window (blockIdx>>4)
// ---------------------------------------------------------------------------
__global__ __launch_bounds__(1024) void simtopk_kernel(
    const float* __restrict__ x,    // (64, 256, 32) fp32
    float* __restrict__ feat)       // (16384, 48)   [16 scores | 32 relpos]
{
    __shared__ float4 xs4[256 * 8];          // 32 KB, slot-swizzled rows
    __shared__ double rs[16][NCAND];         // re-rank scores per wave
    __shared__ int    rj[16][NCAND];         // re-rank indices per wave

    const int tid  = threadIdx.x;
    const int win  = blockIdx.x >> 4;
    const int grp  = blockIdx.x & 15;
    const int lane = tid & 63;
    const int wv   = tid >> 6;

    // stage window (coalesced float4), swizzle slot = f ^ (j&7)
    const float4* gx = reinterpret_cast<const float4*>(x + (size_t)win * 8192);
    #pragma unroll
    for (int k = 0; k < 2; ++k) {
        int v = tid + k * 1024;              // 0..2047
        int j = v >> 3, f = v & 7;
        xs4[j * 8 + (f ^ (j & 7))] = gx[v];
    }
    __syncthreads();

    const int i = grp * 16 + wv;

    // broadcast-load row i into fp32 regs (same in every lane)
    float xi[32];
    #pragma unroll
    for (int f = 0; f < 8; ++f) {
        float4 av = xs4[i * 8 + (f ^ (i & 7))];
        xi[4*f+0] = av.x; xi[4*f+1] = av.y; xi[4*f+2] = av.z; xi[4*f+3] = av.w;
    }

    // fp32 |delta| sums, packed (score_hi24 | idx8): lane owns j = lane + 64q
    unsigned int p[4];
    #pragma unroll
    for (int q = 0; q < 4; ++q) {
        const int j  = q * 64 + lane;
        const int jb = j * 8, jm = j & 7;
        float acc = 0.0f;
        #pragma unroll
        for (int f = 0; f < 8; ++f) {
            float4 bv = xs4[jb + (f ^ jm)];
            acc += fabsf(xi[4*f+0] - bv.x);
            acc += fabsf(xi[4*f+1] - bv.y);
            acc += fabsf(xi[4*f+2] - bv.z);
            acc += fabsf(xi[4*f+3] - bv.w);
        }
        p[q] = (__float_as_uint(acc) & 0xFFFFFF00u) | (unsigned int)j;
    }

    // extract top-NCAND by packed value (unique per j -> exact invalidation)
    int myj = -1;                            // lane k < NCAND gets candidate k
    for (int k = 0; k < NCAND; ++k) {
        unsigned int b = min(min(p[0], p[1]), min(p[2], p[3]));
        #pragma unroll
        for (int m = 32; m >= 1; m >>= 1)
            b = min(b, (unsigned int)__shfl_xor((int)b, m, 64));
        if (lane == k) myj = (int)(b & 0xFFu);
        #pragma unroll
        for (int q = 0; q < 4; ++q)
            if (p[q] == b) p[q] = 0xFFFFFFFFu;
    }

    // fp64 re-rank of the NCAND candidates (lanes 0..NCAND-1)
    double s = 0.0;
    if (myj >= 0) {
        const int jb = myj * 8, jm = myj & 7;
        #pragma unroll
        for (int f = 0; f < 8; ++f) {
            float4 bv = xs4[jb + (f ^ jm)];
            s += fabs((double)xi[4*f+0] - (double)bv.x);
            s += fabs((double)xi[4*f+1] - (double)bv.y);
            s += fabs((double)xi[4*f+2] - (double)bv.z);
            s += fabs((double)xi[4*f+3] - (double)bv.w);
        }
        rs[wv][lane] = s;
        rj[wv][lane] = myj;
    }
    __syncthreads();

    if (myj >= 0) {
        int rank = 0;
        #pragma unroll 4
        for (int o = 0; o < NCAND; ++o) {
            double so = rs[wv][o];
            int    jo = rj[wv][o];
            rank += (so < s || (so == s && jo < myj)) ? 1 : 0;
        }
        if (rank < K_SEL) {
            const int gp = win * 256 + i;
            feat[gp * 48 + rank] = (float)(1.0 - s * 0.03125);
            float dh = (float)((i >> 4) - (myj >> 4)) * (1.0f / 15.0f);
            float dw = (float)((i & 15) - (myj & 15)) * (1.0f / 15.0f);
            reinterpret_cast<float2*>(feat)[gp * 24 + 8 + rank] = make_float2(dh, dw);
        }
    }
}

// ---------------------------------------------------------------------------
// Kernel B v2: both FFNs. block = 1024 thr = 64 px (lane) x 16 waves.
// Wave wv owns neurons [8wv,8wv+8) for 128-wide layers, [4wv,4wv+4) for 64-wide.
// Weights via wave-uniform scalar loads; activations via ds_read_b128,
// LDS rows stride 33 float4 (odd) for minimal b128 bank aliasing.
// ---------------------------------------------------------------------------
template<int IN4, int STR4, int LDW, int NOUT>
__device__ __forceinline__ void ffn_layer(const float4* __restrict__ in4, int px,
                                          const float* __restrict__ W,
                                          const float* __restrict__ B,
                                          int nb, float* acc)
{
    #pragma unroll
    for (int n = 0; n < NOUT; ++n) acc[n] = B[nb + n];
    #pragma unroll 2
    for (int c4 = 0; c4 < IN4; ++c4) {
        float4 a4 = in4[px * STR4 + c4];
        const float* w0 = W + (4 * c4 + 0) * LDW + nb;
        const float* w1 = W + (4 * c4 + 1) * LDW + nb;
        const float* w2 = W + (4 * c4 + 2) * LDW + nb;
        const float* w3 = W + (4 * c4 + 3) * LDW + nb;
        #pragma unroll
        for (int n = 0; n < NOUT; ++n) {
            float a = acc[n];
            a = fmaf(a4.x, w0[n], a);
            a = fmaf(a4.y, w1[n], a);
            a = fmaf(a4.z, w2[n], a);
            a = fmaf(a4.w, w3[n], a);
            acc[n] = a;
        }
    }
}

__global__ __launch_bounds__(1024, 4) void ffn_kernel(
    const float* __restrict__ x,     // (16384, 32)
    const float* __restrict__ feat,  // (16384, 48)
    const float* __restrict__ s0w, const float* __restrict__ s0b,   // 48x128
    const float* __restrict__ s1w, const float* __restrict__ s1b,   // 128x128
    const float* __restrict__ sow, const float* __restrict__ sob,   // 128x64
    const float* __restrict__ o0w, const float* __restrict__ o0b,   // 96x128
    const float* __restrict__ o1w, const float* __restrict__ o1b,   // 128x128
    const float* __restrict__ oow, const float* __restrict__ oob,   // 128x64
    float* __restrict__ out)         // (16384, 64)
{
    __shared__ float4 fs4[64 * 13];      // feat rows, 12 f4 + 1 pad
    __shared__ float4 A4[64 * 33];       // 32 f4 + 1 pad
    __shared__ float4 B4[64 * 33];

    const int tid   = threadIdx.x;
    const int px    = tid & 63;
    const int wv    = tid >> 6;                                  // 0..15
    const int nb8   = __builtin_amdgcn_readfirstlane(wv * 8);
    const int nb4   = __builtin_amdgcn_readfirstlane(wv * 4);
    const int sl8   = __builtin_amdgcn_readfirstlane(wv * 2);    // f4 slot for 8-neuron grp
    const int slsf  = __builtin_amdgcn_readfirstlane(8 + wv);    // f4 slot for sf grp
    const int pbase = blockIdx.x * 64;

    // stage feat rows (coalesced float4): 64 px x 12 f4 = 768
    if (tid < 768) {
        int p = tid / 12, f = tid - p * 12;
        fs4[p * 13 + f] = reinterpret_cast<const float4*>(feat)[(size_t)pbase * 12 + tid];
    }
    __syncthreads();

    float acc[8];

    // L1: 48 -> 128 relu   (fs4 -> A4 slots 0..31)
    ffn_layer<12, 13, 128, 8>(fs4, px, s0w, s0b, nb8, acc);
    A4[px * 33 + sl8    ] = make_float4(fmaxf(acc[0],0.f), fmaxf(acc[1],0.f), fmaxf(acc[2],0.f), fmaxf(acc[3],0.f));
    A4[px * 33 + sl8 + 1] = make_float4(fmaxf(acc[4],0.f), fmaxf(acc[5],0.f), fmaxf(acc[6],0.f), fmaxf(acc[7],0.f));
    __syncthreads();

    // L2: 128 -> 128 relu  (A4 -> B4)
    ffn_layer<32, 33, 128, 8>(A4, px, s1w, s1b, nb8, acc);
    B4[px * 33 + sl8    ] = make_float4(fmaxf(acc[0],0.f), fmaxf(acc[1],0.f), fmaxf(acc[2],0.f), fmaxf(acc[3],0.f));
    B4[px * 33 + sl8 + 1] = make_float4(fmaxf(acc[4],0.f), fmaxf(acc[5],0.f), fmaxf(acc[6],0.f), fmaxf(acc[7],0.f));
    __syncthreads();

    // Phase 3: stage x into A4 slots 0..7  +  L3: 128 -> 64 (sf, no relu) into A4 slots 8..23
    if (tid < 512) {
        int p = tid >> 3, f = tid & 7;
        A4[p * 33 + f] = reinterpret_cast<const float4*>(x)[(size_t)(pbase + p) * 8 + f];
    }
    ffn_layer<32, 33, 64, 4>(B4, px, sow, sob, nb4, acc);
    A4[px * 33 + slsf] = make_float4(acc[0], acc[1], acc[2], acc[3]);
    __syncthreads();

    // L4: [x(32) | sf(64)] = 96 -> 128 relu  (A4 slots 0..23 -> B4); weight row = 4*c4+cc
    ffn_layer<24, 33, 128, 8>(A4, px, o0w, o0b, nb8, acc);
    B4[px * 33 + sl8    ] = make_float4(fmaxf(acc[0],0.f), fmaxf(acc[1],0.f), fmaxf(acc[2],0.f), fmaxf(acc[3],0.f));
    B4[px * 33 + sl8 + 1] = make_float4(fmaxf(acc[4],0.f), fmaxf(acc[5],0.f), fmaxf(acc[6],0.f), fmaxf(acc[7],0.f));
    __syncthreads();

    // L5: 128 -> 128 relu  (B4 -> A4)
    ffn_layer<32, 33, 128, 8>(B4, px, o1w, o1b, nb8, acc);
    A4[px * 33 + sl8    ] = make_float4(fmaxf(acc[0],0.f), fmaxf(acc[1],0.f), fmaxf(acc[2],0.f), fmaxf(acc[3],0.f));
    A4[px * 33 + sl8 + 1] = make_float4(fmaxf(acc[4],0.f), fmaxf(acc[5],0.f), fmaxf(acc[6],0.f), fmaxf(acc[7],0.f));
    __syncthreads();

    // L6: 128 -> 64 (+bias, no relu) -> out (float4 per thread)
    ffn_layer<32, 33, 64, 4>(A4, px, oow, oob, nb4, acc);
    reinterpret_cast<float4*>(out)[(size_t)(pbase + px) * 16 + (nb4 >> 2)] =
        make_float4(acc[0], acc[1], acc[2], acc[3]);
}

extern "C" void kernel_launch(void* const* d_in, const int* in_sizes, int n_in,
                              void* d_out, int out_size, void* d_ws, size_t ws_size,
                              hipStream_t stream) {
    const float* x    = (const float*)d_in[0];
    const float* s0w  = (const float*)d_in[1];
    const float* s0b  = (const float*)d_in[2];
    const float* s1w  = (const float*)d_in[3];
    const float* s1b  = (const float*)d_in[4];
    const float* sow  = (const float*)d_in[5];
    const float* sob  = (const float*)d_in[6];
    const float* o0w  = (const float*)d_in[7];
    const float* o0b  = (const float*)d_in[8];
    const float* o1w  = (const float*)d_in[9];
    const float* o1b  = (const float*)d_in[10];
    const float* oow  = (const float*)d_in[11];
    const float* oob  = (const float*)d_in[12];
    float* feat = (float*)d_ws;                  // 16384 * 48 fp32 = 3.1 MB
    float* out  = (float*)d_out;

    simtopk_kernel<<<1024, 1024, 0, stream>>>(x, feat);
    ffn_kernel<<<256, 1024, 0, stream>>>(x, feat,
                                         s0w, s0b, s1w, s1b, sow, sob,
                                         o0w, o0b, o1w, o1b, oow, oob,
                                         out);
}